// Round 12
// baseline (325.049 us; speedup 1.0000x reference)
//
#include <hip/hip_runtime.h>
#include <stdint.h>

typedef unsigned short u16;
typedef unsigned int u32;
typedef float f32x4 __attribute__((ext_vector_type(4)));
typedef float f32x8 __attribute__((ext_vector_type(8)));
typedef int   i32x4 __attribute__((ext_vector_type(4)));
typedef __bf16 bf16x8 __attribute__((ext_vector_type(8)));
typedef u16 u16x4 __attribute__((ext_vector_type(4)));

constexpr int S_LEN = 4096;
constexpr int HID   = 2048;
constexpr int WIN   = 2048;

__device__ __forceinline__ u32 f2bf_u(float f) {
  u32 u = __builtin_bit_cast(u32, f);
  return (u + 0x7fffu + ((u >> 16) & 1u)) >> 16;
}
__device__ __forceinline__ float bf2f(u16 u) {
  return __builtin_bit_cast(float, ((u32)u) << 16);
}
__device__ __forceinline__ float exp2x(float x) {
#if __has_builtin(__builtin_amdgcn_exp2f)
  return __builtin_amdgcn_exp2f(x);
#else
  return exp2f(x);
#endif
}
__device__ __forceinline__ void mfma16(f32x4& acc, i32x4 a, i32x4 b) {
  acc = __builtin_amdgcn_mfma_f32_16x16x32_bf16(
      __builtin_bit_cast(bf16x8, a), __builtin_bit_cast(bf16x8, b), acc, 0, 0, 0);
}
__device__ __forceinline__ void gload_lds16(const u16* g, u16* l) {
  __builtin_amdgcn_global_load_lds((const __attribute__((address_space(1))) u32*)g,
                                   (__attribute__((address_space(3))) u32*)l, 16, 0, 0);
}

// -------- fused fp32 -> bf16 convert (5 tensors) + RoPE cos/sin table -------
constexpr int CVT_B0 = 1048576;            // X
constexpr int CVT_B1 = CVT_B0 + 524288;    // +Wq
constexpr int CVT_B2 = CVT_B1 + 131072;    // +Wk
constexpr int CVT_B3 = CVT_B2 + 131072;    // +Wv
constexpr int CVT_B4 = CVT_B3 + 524288;    // +Wo
constexpr int CVT_B5 = CVT_B4 + 32768;     // +rope table (S*64/8 threads)

__global__ __launch_bounds__(256) void cvt_all_kernel(
    const float* __restrict__ s0, const float* __restrict__ s1,
    const float* __restrict__ s2, const float* __restrict__ s3,
    const float* __restrict__ s4, u16* __restrict__ d0, u16* __restrict__ d1,
    u16* __restrict__ d2, u16* __restrict__ d3, u16* __restrict__ d4,
    float* __restrict__ cs, float* __restrict__ sn) {
  int t = blockIdx.x * 256 + threadIdx.x;
  if (t >= CVT_B4) {
    if (t >= CVT_B5) return;
    // rope table: 8 consecutive (s,d) entries per thread
    int e = (t - CVT_B4) * 8;
    int d = e & 63, s = e >> 6;
#pragma unroll
    for (int j = 0; j < 8; ++j) {
      float inv = exp2f(-(float)(d + j) * 0.20762050593046014f);  // log2(1e4)/64
      float f = (float)s * inv;
      cs[e + j] = cosf(f);
      sn[e + j] = sinf(f);
    }
    return;
  }
  const float* s;
  u16* d;
  int off;
  if (t < CVT_B0) { s = s0; d = d0; off = t; }
  else if (t < CVT_B1) { s = s1; d = d1; off = t - CVT_B0; }
  else if (t < CVT_B2) { s = s2; d = d2; off = t - CVT_B1; }
  else if (t < CVT_B3) { s = s3; d = d3; off = t - CVT_B2; }
  else { s = s4; d = d4; off = t - CVT_B3; }
  const f32x4* sp = (const f32x4*)s + (size_t)off * 2;
  f32x4 a = sp[0], b = sp[1];
  i32x4 o;
  o.x = (int)(f2bf_u(a.x) | (f2bf_u(a.y) << 16));
  o.y = (int)(f2bf_u(a.z) | (f2bf_u(a.w) << 16));
  o.z = (int)(f2bf_u(b.x) | (f2bf_u(b.y) << 16));
  o.w = (int)(f2bf_u(b.z) | (f2bf_u(b.w) << 16));
  *((i32x4*)d + off) = o;
}

// ---------------- fused in-place RoPE on Q (scaled) and K ----------------
// Q additionally multiplied by 1/sqrt(128)*log2(e) (softmax runs in exp2 domain)
__global__ __launch_bounds__(256) void rope_qk_kernel(u16* __restrict__ Qb,
                                                      u16* __restrict__ Kb,
                                                      const float* __restrict__ cs,
                                                      const float* __restrict__ sn) {
  const float SC2 = 0.088388347648318447f * 1.4426950408889634f;
  int t = blockIdx.x * 256 + threadIdx.x;  // S*(16+4)*16 threads
  int d0 = (t & 15) * 4;
  int r = t >> 4;
  u16* p;
  int s;
  float qs;
  if (r < S_LEN * 16) {
    int h = r & 15; s = r >> 4;
    p = Qb + (size_t)s * HID + h * 128 + d0;
    qs = SC2;
  } else {
    int r2 = r - S_LEN * 16;
    int h = r2 & 3; s = r2 >> 2;
    p = Kb + (size_t)s * 512 + h * 128 + d0;
    qs = 1.f;
  }
  f32x4 c = *(const f32x4*)&cs[(s << 6) | d0];
  f32x4 si = *(const f32x4*)&sn[(s << 6) | d0];
  u16x4 a = *(u16x4*)p, b = *(u16x4*)(p + 64);
  u16x4 oa, ob;
#pragma unroll
  for (int j = 0; j < 4; ++j) {
    float x1 = bf2f(a[j]), x2 = bf2f(b[j]);
    oa[j] = (u16)f2bf_u((x1 * c[j] - x2 * si[j]) * qs);
    ob[j] = (u16)f2bf_u((x2 * c[j] + x1 * si[j]) * qs);
  }
  *(u16x4*)p = oa;
  *(u16x4*)(p + 64) = ob;
}

// ---------------- fused QKV GEMM: X[4096x2048] x {Wq,Wk,Wv}^T ----------------
__global__ __launch_bounds__(256) void qkv_gemm_kernel(
    const u16* __restrict__ A, const u16* __restrict__ Wq,
    const u16* __restrict__ Wk, const u16* __restrict__ Wv,
    u16* __restrict__ Qb, u16* __restrict__ Kb, u16* __restrict__ Vt) {
  __shared__ __attribute__((aligned(16))) u16 sA[128 * 64];
  __shared__ __attribute__((aligned(16))) u16 sB[128 * 64];
  const int lane = threadIdx.x & 63;
  const int w = threadIdx.x >> 6;
  const int g = lane >> 4, ln = lane & 15;
  const int K = HID;

  int wgid = blockIdx.x;                 // 768
  wgid = (wgid & 7) * 96 + (wgid >> 3);  // bijective XCD swizzle
  const int brow = (wgid / 24) * 128;
  const int bcol = (wgid % 24) * 128;

  const u16* B;
  u16* out;
  int bc, mode, N;
  if (bcol < 2048)      { B = Wq; out = Qb; bc = bcol;        N = 2048; mode = 0; }
  else if (bcol < 2560) { B = Wk; out = Kb; bc = bcol - 2048; N = 512;  mode = 0; }
  else                  { B = Wv; out = Vt; bc = bcol - 2560; N = 512;  mode = 1; }

  const int wr = (w >> 1) * 64, wc = (w & 1) * 64;
  f32x4 acc[4][4] = {};

  const int sr = w * 32 + (lane >> 3);
  const int scol = (lane & 7) * 8;
  const u16* Abase = A + (size_t)(brow + sr) * K + scol;
  const u16* Bbase = B + (size_t)(bc + sr) * K + scol;
  u16* sAdst = &sA[w * 2048];
  u16* sBdst = &sB[w * 2048];

  for (int k0 = 0; k0 < K; k0 += 64) {
    __syncthreads();
#pragma unroll
    for (int i = 0; i < 4; ++i) {
      gload_lds16(Abase + (size_t)i * 8 * K + k0, sAdst + i * 512);
      gload_lds16(Bbase + (size_t)i * 8 * K + k0, sBdst + i * 512);
    }
    __syncthreads();
#pragma unroll
    for (int kk = 0; kk < 2; ++kk) {
      i32x4 af[4], bfr[4];
#pragma unroll
      for (int m = 0; m < 4; ++m)
        af[m] = *(const i32x4*)&sA[(wr + m * 16 + ln) * 64 + kk * 32 + g * 8];
#pragma unroll
      for (int n = 0; n < 4; ++n)
        bfr[n] = *(const i32x4*)&sB[(wc + n * 16 + ln) * 64 + kk * 32 + g * 8];
#pragma unroll
      for (int m = 0; m < 4; ++m)
#pragma unroll
        for (int n = 0; n < 4; ++n) mfma16(acc[m][n], af[m], bfr[n]);
    }
  }

  const int orow0 = brow + wr + g * 4;
  const int ocol0 = bc + wc + ln;
#pragma unroll
  for (int m = 0; m < 4; ++m)
#pragma unroll
    for (int n = 0; n < 4; ++n)
#pragma unroll
      for (int j = 0; j < 4; ++j) {
        int row = orow0 + m * 16 + j;
        int col = ocol0 + n * 16;
        float v = acc[m][n][j];
        if (mode == 0) {
          out[(size_t)row * N + col] = (u16)f2bf_u(v);
        } else {
          int d = col & 127, kvh = col >> 7;
          int T = row >> 5, ks = row & 31;
          int tt = ks >> 4, gg = (ks >> 2) & 3, e = (tt << 2) | (ks & 3);
          size_t idx = (size_t)kvh * S_LEN * 128 + (size_t)T * 4096 +
                       (size_t)d * 32 + ((size_t)(gg ^ ((d >> 1) & 3)) << 3) + e;
          out[idx] = (u16)f2bf_u(v);
        }
      }
}

// ---------------- O-projection GEMM: fp32 out ----------------
__global__ __launch_bounds__(256) void gemm_o_kernel(const u16* __restrict__ A,
                                                     const u16* __restrict__ B,
                                                     float* __restrict__ Cv,
                                                     int K, int N) {
  __shared__ __attribute__((aligned(16))) u16 sA[128 * 64];
  __shared__ __attribute__((aligned(16))) u16 sB[128 * 64];
  const int lane = threadIdx.x & 63;
  const int w = threadIdx.x >> 6;
  const int g = lane >> 4, ln = lane & 15;

  int wgid = blockIdx.y * gridDim.x + blockIdx.x;
  const int nwg = gridDim.x * gridDim.y;
  wgid = (wgid & 7) * (nwg >> 3) + (wgid >> 3);
  const int brow = (wgid / gridDim.x) * 128;
  const int bcol = (wgid % gridDim.x) * 128;
  const int wr = (w >> 1) * 64, wc = (w & 1) * 64;

  f32x4 acc[4][4] = {};

  const int sr = w * 32 + (lane >> 3);
  const int scol = (lane & 7) * 8;
  const u16* Abase = A + (size_t)(brow + sr) * K + scol;
  const u16* Bbase = B + (size_t)(bcol + sr) * K + scol;
  u16* sAdst = &sA[w * 2048];
  u16* sBdst = &sB[w * 2048];

  for (int k0 = 0; k0 < K; k0 += 64) {
    __syncthreads();
#pragma unroll
    for (int i = 0; i < 4; ++i) {
      gload_lds16(Abase + (size_t)i * 8 * K + k0, sAdst + i * 512);
      gload_lds16(Bbase + (size_t)i * 8 * K + k0, sBdst + i * 512);
    }
    __syncthreads();
#pragma unroll
    for (int kk = 0; kk < 2; ++kk) {
      i32x4 af[4], bfr[4];
#pragma unroll
      for (int m = 0; m < 4; ++m)
        af[m] = *(const i32x4*)&sA[(wr + m * 16 + ln) * 64 + kk * 32 + g * 8];
#pragma unroll
      for (int n = 0; n < 4; ++n)
        bfr[n] = *(const i32x4*)&sB[(wc + n * 16 + ln) * 64 + kk * 32 + g * 8];
#pragma unroll
      for (int m = 0; m < 4; ++m)
#pragma unroll
        for (int n = 0; n < 4; ++n) mfma16(acc[m][n], af[m], bfr[n]);
    }
  }

  const int orow0 = brow + wr + g * 4;
  const int ocol0 = bcol + wc + ln;
#pragma unroll
  for (int m = 0; m < 4; ++m)
#pragma unroll
    for (int n = 0; n < 4; ++n)
#pragma unroll
      for (int j = 0; j < 4; ++j)
        Cv[(size_t)(orow0 + m * 16 + j) * N + ocol0 + n * 16] = acc[m][n][j];
}

// ---------------- flash attention: 4 independent waves / block ----------------
// grid 1024 x 256 thr. Block b: XCD=b&7, gq=127-(b>>3) (all 4 waves same gq ->
// equal durations); wave w: head=((b&7)<<1)|(w>>1), chunk=w&1. No LDS/barriers.
// K/V global->regs, exp2-domain softmax, T15 QK(t+1)-before-softmax(t) pipeline.
__global__ __launch_bounds__(256) void attn_kernel(const u16* __restrict__ Q,
                                                   const u16* __restrict__ Kb,
                                                   const u16* __restrict__ Vt,
                                                   u16* __restrict__ opart,
                                                   float* __restrict__ mpart,
                                                   float* __restrict__ lpart) {
  const int lane = threadIdx.x & 63;
  const int w = threadIdx.x >> 6;
  const int g = lane >> 4, ln = lane & 15;

  const int b = blockIdx.x;                 // 1024
  const int h = ((b & 7) << 1) | (w >> 1);  // 2 heads per XCD
  const int chunk = w & 1;
  const int gq = 127 - (b >> 3);            // heavy q-groups first
  const int kvh = h >> 2;
  const int qr0 = gq * 32;

  i32x4 aq[2][4];
#pragma unroll
  for (int qf = 0; qf < 2; ++qf) {
    const u16* qp = Q + (size_t)(qr0 + qf * 16 + ln) * HID + h * 128 + g * 8;
#pragma unroll
    for (int c = 0; c < 4; ++c) aq[qf][c] = *(const i32x4*)(qp + c * 32);
  }

  f32x4 oacc[2][8] = {};
  float mrun[2] = {-1e30f, -1e30f};
  float lrun[2] = {0.f, 0.f};  // per-lane partial; cross-lane reduce at end

  int lo = qr0 - (WIN - 1);
  if (lo < 0) lo = 0;
  lo &= ~31;
  const int nt_full = ((qr0 + 32) - lo) >> 5;
  const int nt0 = nt_full >> 1;
  const int lo_c = lo + (chunk ? nt0 * 32 : 0);
  const int nt = chunk ? nt_full - nt0 : nt0;

  const u16* kptr0 = Kb + (size_t)(lo_c + ln) * 512 + kvh * 128 + g * 8;
  const int vswz = (g ^ ((ln >> 1) & 3)) << 3;
  const u16* vptr0 = Vt + (size_t)kvh * S_LEN * 128 +
                     (size_t)(lo_c >> 5) * 4096 + ln * 32 + vswz;

  i32x4 kfN[2][4], vf[8];
  f32x4 scA[2][2], scB[2][2];

#define TILE_P(T, SCC, SCN)                                                    \
  {                                                                            \
    const int kb = lo_c + (T) * 32;                                            \
    if ((T) + 1 < nt) { /* issue QK(T+1) before softmax(T): hides under VALU */\
      SCN[0][0] = (f32x4){};                                                   \
      SCN[0][1] = (f32x4){};                                                   \
      SCN[1][0] = (f32x4){};                                                   \
      SCN[1][1] = (f32x4){};                                                   \
      __builtin_amdgcn_s_setprio(1);                                           \
      _Pragma("unroll") for (int c = 0; c < 4; ++c) {                          \
        mfma16(SCN[0][0], kfN[0][c], aq[0][c]);                                \
        mfma16(SCN[0][1], kfN[1][c], aq[0][c]);                                \
        mfma16(SCN[1][0], kfN[0][c], aq[1][c]);                                \
        mfma16(SCN[1][1], kfN[1][c], aq[1][c]);                                \
      }                                                                        \
      __builtin_amdgcn_s_setprio(0);                                           \
      if ((T) + 2 < nt) { /* refill kfN with K(T+2) */                         \
        const u16* kp = kptr0 + (size_t)((T) + 2) * 16384;                     \
        _Pragma("unroll") for (int tt = 0; tt < 2; ++tt)                       \
          _Pragma("unroll") for (int c = 0; c < 4; ++c)                        \
            kfN[tt][c] = *(const i32x4*)(kp + tt * 8192 + c * 32);             \
      }                                                                        \
    }                                                                          \
    float p[2][8], mx[2];                                                      \
    const bool interior = (kb + 31 <= qr0) && (qr0 + 31 - kb < WIN);           \
    _Pragma("unroll") for (int qf = 0; qf < 2; ++qf) {                         \
      if (interior) {                                                          \
        _Pragma("unroll") for (int j = 0; j < 4; ++j) {                        \
          p[qf][j] = SCC[qf][0][j];                                            \
          p[qf][4 + j] = SCC[qf][1][j];                                        \
        }                                                                      \
      } else {                                                                 \
        const float NEG = -__builtin_inff();                                   \
        const int q = qr0 + qf * 16 + ln;                                      \
        _Pragma("unroll") for (int tt = 0; tt < 2; ++tt)                       \
          _Pragma("unroll") for (int j = 0; j < 4; ++j) {                      \
            int k = kb + tt * 16 + g * 4 + j;                                  \
            p[qf][tt * 4 + j] = (k <= q && q - k < WIN) ? SCC[qf][tt][j] : NEG;\
          }                                                                    \
      }                                                                        \
      float x0 = fmaxf(fmaxf(p[qf][0], p[qf][1]), p[qf][2]);                   \
      float x1 = fmaxf(fmaxf(p[qf][3], p[qf][4]), p[qf][5]);                   \
      float x2 = fmaxf(fmaxf(p[qf][6], p[qf][7]), x0);                         \
      float m = fmaxf(x1, x2);                                                 \
      m = fmaxf(m, __shfl_xor(m, 16));                                         \
      m = fmaxf(m, __shfl_xor(m, 32));                                         \
      mx[qf] = m;                                                              \
    }                                                                          \
    float corr[2] = {1.f, 1.f};                                                \
    const bool noskip =                                                        \
        !__all((mx[0] - mrun[0] <= 11.f) && (mx[1] - mrun[1] <= 11.f));        \
    if (noskip) {                                                              \
      _Pragma("unroll") for (int qf = 0; qf < 2; ++qf) {                       \
        float mnew = fmaxf(mrun[qf], mx[qf]);                                  \
        corr[qf] = exp2x(mrun[qf] - mnew);                                     \
        mrun[qf] = mnew;                                                       \
        f32x4 cv;                                                              \
        _Pragma("unroll") for (int j = 0; j < 4; ++j)                          \
            cv[j] = __shfl(corr[qf], g * 4 + j);                               \
        _Pragma("unroll") for (int nf = 0; nf < 8; ++nf)                       \
          _Pragma("unroll") for (int j = 0; j < 4; ++j)                        \
              oacc[qf][nf][j] *= cv[j];                                        \
      }                                                                        \
    }                                                                          \
    i32x4 pa[2];                                                               \
    _Pragma("unroll") for (int qf = 0; qf < 2; ++qf) {                         \
      f32x8 pv;                                                                \
      _Pragma("unroll") for (int e = 0; e < 8; ++e)                            \
          pv[e] = exp2x(p[qf][e] - mrun[qf]);                                  \
      float rs = ((pv[0] + pv[1]) + (pv[2] + pv[3])) +                         \
                 ((pv[4] + pv[5]) + (pv[6] + pv[7]));                          \
      lrun[qf] = lrun[qf] * corr[qf] + rs;                                     \
      bf16x8 pb = __builtin_convertvector(pv, bf16x8);                         \
      pa[qf] = __builtin_bit_cast(i32x4, pb);                                  \
    }                                                                          \
    __builtin_amdgcn_s_setprio(1);                                             \
    _Pragma("unroll") for (int nf = 0; nf < 8; ++nf) {                         \
      mfma16(oacc[0][nf], pa[0], vf[nf]);                                      \
      mfma16(oacc[1][nf], pa[1], vf[nf]);                                      \
    }                                                                          \
    __builtin_amdgcn_s_setprio(0);                                             \
    if ((T) + 1 < nt) { /* refill vf with V(T+1) */                            \
      const u16* vp = vptr0 + (size_t)((T) + 1) * 4096;                        \
      _Pragma("unroll") for (int nf = 0; nf < 8; ++nf)                         \
          vf[nf] = *(const i32x4*)(vp + nf * 512);                             \
    }                                                                          \
  }

  if (nt > 0) {
    // prologue: load K(0), V(0); compute QK(0) -> scA; refill kfN = K(1)
#pragma unroll
    for (int tt = 0; tt < 2; ++tt)
#pragma unroll
      for (int c = 0; c < 4; ++c)
        kfN[tt][c] = *(const i32x4*)(kptr0 + tt * 8192 + c * 32);
#pragma unroll
    for (int nf = 0; nf < 8; ++nf) vf[nf] = *(const i32x4*)(vptr0 + nf * 512);
    scA[0][0] = (f32x4){};
    scA[0][1] = (f32x4){};
    scA[1][0] = (f32x4){};
    scA[1][1] = (f32x4){};
    __builtin_amdgcn_s_setprio(1);
#pragma unroll
    for (int c = 0; c < 4; ++c) {
      mfma16(scA[0][0], kfN[0][c], aq[0][c]);
      mfma16(scA[0][1], kfN[1][c], aq[0][c]);
      mfma16(scA[1][0], kfN[0][c], aq[1][c]);
      mfma16(scA[1][1], kfN[1][c], aq[1][c]);
    }
    __builtin_amdgcn_s_setprio(0);
    if (1 < nt) {
      const u16* kp = kptr0 + 16384;
#pragma unroll
      for (int tt = 0; tt < 2; ++tt)
#pragma unroll
        for (int c = 0; c < 4; ++c)
          kfN[tt][c] = *(const i32x4*)(kp + tt * 8192 + c * 32);
    }

    int t = 0;
    for (; t + 1 < nt; t += 2) {
      TILE_P(t, scA, scB);
      TILE_P(t + 1, scB, scA);
    }
    if (t < nt) TILE_P(t, scA, scB);
  }
#undef TILE_P

  // finish deferred cross-lane l reduction
#pragma unroll
  for (int qf = 0; qf < 2; ++qf) {
    float l = lrun[qf];
    l += __shfl_xor(l, 16);
    l += __shfl_xor(l, 32);
    lrun[qf] = l;
  }

  const size_t pb = ((size_t)chunk * 16 + h) * S_LEN;
#pragma unroll
  for (int qf = 0; qf < 2; ++qf) {
    if (g == 0) {
      mpart[pb + qr0 + qf * 16 + ln] = mrun[qf];  // log2-domain
      lpart[pb + qr0 + qf * 16 + ln] = lrun[qf];
    }
    u16* aop = opart + (pb + qr0 + qf * 16 + g * 4) * 128 + ln;
#pragma unroll
    for (int j = 0; j < 4; ++j)
#pragma unroll
      for (int nf = 0; nf < 8; ++nf)
        aop[(size_t)j * 128 + nf * 16] = (u16)f2bf_u(oacc[qf][nf][j]);
  }
}

// ---------------- combine partials (log2-domain m) -> AO bf16 ----------------
__global__ __launch_bounds__(256) void attn_combine_kernel(
    const u16* __restrict__ opart, const float* __restrict__ mpart,
    const float* __restrict__ lpart, u16* __restrict__ AO) {
  int t = blockIdx.x * 256 + threadIdx.x;  // 16*4096*16 threads
  int d0 = (t & 15) * 8;
  int rh = t >> 4;
  int row = rh & (S_LEN - 1);
  int h = rh >> 12;
  size_t i0 = (size_t)h * S_LEN + row;
  size_t i1 = i0 + (size_t)16 * S_LEN;
  float m0 = mpart[i0], m1 = mpart[i1];
  float l0 = lpart[i0], l1 = lpart[i1];
  float m = fmaxf(m0, m1);
  float w0 = exp2x(m0 - m), w1 = exp2x(m1 - m);
  float inv = 1.f / (l0 * w0 + l1 * w1);
  w0 *= inv;
  w1 *= inv;
  i32x4 v0 = *(const i32x4*)(opart + i0 * 128 + d0);
  i32x4 v1 = *(const i32x4*)(opart + i1 * 128 + d0);
  i32x4 ov;
#pragma unroll
  for (int j = 0; j < 4; ++j) {
    u32 a = ((u32)v0[j]), b = ((u32)v1[j]);
    float x = bf2f((u16)a) * w0 + bf2f((u16)b) * w1;
    float y = bf2f((u16)(a >> 16)) * w0 + bf2f((u16)(b >> 16)) * w1;
    ov[j] = (int)(f2bf_u(x) | (f2bf_u(y) << 16));
  }
  *(i32x4*)(AO + (size_t)row * HID + h * 128 + d0) = ov;
}

// ---------------- orchestration ----------------
extern "C" void kernel_launch(void* const* d_in, const int* in_sizes, int n_in,
                              void* d_out, int out_size, void* d_ws, size_t ws_size,
                              hipStream_t stream) {
  const float* hx = (const float*)d_in[0];
  const float* qw = (const float*)d_in[1];
  const float* kw = (const float*)d_in[2];
  const float* vw = (const float*)d_in[3];
  const float* ow = (const float*)d_in[4];

  char* p = (char*)d_ws;
  u16* Xb = (u16*)p; p += (size_t)S_LEN * HID * 2;
  u16* Wq = (u16*)p; p += (size_t)HID * HID * 2;
  u16* Wk = (u16*)p; p += (size_t)512 * HID * 2;
  u16* Wv = (u16*)p; p += (size_t)512 * HID * 2;
  u16* Wo = (u16*)p; p += (size_t)HID * HID * 2;
  u16* Qb = (u16*)p; p += (size_t)S_LEN * HID * 2;
  u16* Kb = (u16*)p; p += (size_t)S_LEN * 512 * 2;
  u16* Vt = (u16*)p; p += (size_t)S_LEN * 512 * 2;
  u16* AO = (u16*)p; p += (size_t)S_LEN * HID * 2;
  float* cs = (float*)p; p += (size_t)S_LEN * 64 * 4;
  float* sn = (float*)p; p += (size_t)S_LEN * 64 * 4;
  u16* Opart = (u16*)p; p += (size_t)2 * 16 * S_LEN * 128 * 2;  // 32 MB
  float* Mpart = (float*)p; p += (size_t)2 * 16 * S_LEN * 4;
  float* Lpart = (float*)p; p += (size_t)2 * 16 * S_LEN * 4;

  cvt_all_kernel<<<(CVT_B5 + 255) / 256, 256, 0, stream>>>(
      hx, qw, kw, vw, ow, Xb, Wq, Wk, Wv, Wo, cs, sn);

  qkv_gemm_kernel<<<768, 256, 0, stream>>>(Xb, Wq, Wk, Wv, Qb, Kb, Vt);

  rope_qk_kernel<<<S_LEN * 20 * 16 / 256, 256, 0, stream>>>(Qb, Kb, cs, sn);

  attn_kernel<<<1024, 256, 0, stream>>>(Qb, Kb, Vt, Opart, Mpart, Lpart);
  attn_combine_kernel<<<S_LEN * 16 * 16 / 256, 256, 0, stream>>>(Opart, Mpart,
                                                                 Lpart, AO);

  gemm_o_kernel<<<dim3(16, 32), 256, 0, stream>>>(AO, Wo, (float*)d_out, HID,
                                                  HID);
}

// Round 13
// 323.482 us; speedup vs baseline: 1.0048x; 1.0048x over previous
//
#include <hip/hip_runtime.h>
#include <stdint.h>

typedef unsigned short u16;
typedef unsigned int u32;
typedef float f32x4 __attribute__((ext_vector_type(4)));
typedef float f32x8 __attribute__((ext_vector_type(8)));
typedef int   i32x4 __attribute__((ext_vector_type(4)));
typedef __bf16 bf16x8 __attribute__((ext_vector_type(8)));
typedef u16 u16x4 __attribute__((ext_vector_type(4)));

constexpr int S_LEN = 4096;
constexpr int HID   = 2048;
constexpr int WIN   = 2048;

__device__ __forceinline__ u32 f2bf_u(float f) {
  u32 u = __builtin_bit_cast(u32, f);
  return (u + 0x7fffu + ((u >> 16) & 1u)) >> 16;
}
__device__ __forceinline__ float bf2f(u16 u) {
  return __builtin_bit_cast(float, ((u32)u) << 16);
}
__device__ __forceinline__ float exp2x(float x) {
#if __has_builtin(__builtin_amdgcn_exp2f)
  return __builtin_amdgcn_exp2f(x);
#else
  return exp2f(x);
#endif
}
__device__ __forceinline__ void mfma16(f32x4& acc, i32x4 a, i32x4 b) {
  acc = __builtin_amdgcn_mfma_f32_16x16x32_bf16(
      __builtin_bit_cast(bf16x8, a), __builtin_bit_cast(bf16x8, b), acc, 0, 0, 0);
}
__device__ __forceinline__ void gload_lds16(const u16* g, u16* l) {
  __builtin_amdgcn_global_load_lds((const __attribute__((address_space(1))) u32*)g,
                                   (__attribute__((address_space(3))) u32*)l, 16, 0, 0);
}

// -------- fused fp32 -> bf16 convert (5 tensors) + RoPE cos/sin table -------
constexpr int CVT_B0 = 1048576;            // X
constexpr int CVT_B1 = CVT_B0 + 524288;    // +Wq
constexpr int CVT_B2 = CVT_B1 + 131072;    // +Wk
constexpr int CVT_B3 = CVT_B2 + 131072;    // +Wv
constexpr int CVT_B4 = CVT_B3 + 524288;    // +Wo
constexpr int CVT_B5 = CVT_B4 + 32768;     // +rope table (S*64/8 threads)

__global__ __launch_bounds__(256) void cvt_all_kernel(
    const float* __restrict__ s0, const float* __restrict__ s1,
    const float* __restrict__ s2, const float* __restrict__ s3,
    const float* __restrict__ s4, u16* __restrict__ d0, u16* __restrict__ d1,
    u16* __restrict__ d2, u16* __restrict__ d3, u16* __restrict__ d4,
    float* __restrict__ cs, float* __restrict__ sn) {
  int t = blockIdx.x * 256 + threadIdx.x;
  if (t >= CVT_B4) {
    if (t >= CVT_B5) return;
    int e = (t - CVT_B4) * 8;
    int d = e & 63, s = e >> 6;
#pragma unroll
    for (int j = 0; j < 8; ++j) {
      float inv = exp2f(-(float)(d + j) * 0.20762050593046014f);  // log2(1e4)/64
      float f = (float)s * inv;
      cs[e + j] = cosf(f);
      sn[e + j] = sinf(f);
    }
    return;
  }
  const float* s;
  u16* d;
  int off;
  if (t < CVT_B0) { s = s0; d = d0; off = t; }
  else if (t < CVT_B1) { s = s1; d = d1; off = t - CVT_B0; }
  else if (t < CVT_B2) { s = s2; d = d2; off = t - CVT_B1; }
  else if (t < CVT_B3) { s = s3; d = d3; off = t - CVT_B2; }
  else { s = s4; d = d4; off = t - CVT_B3; }
  const f32x4* sp = (const f32x4*)s + (size_t)off * 2;
  f32x4 a = sp[0], b = sp[1];
  i32x4 o;
  o.x = (int)(f2bf_u(a.x) | (f2bf_u(a.y) << 16));
  o.y = (int)(f2bf_u(a.z) | (f2bf_u(a.w) << 16));
  o.z = (int)(f2bf_u(b.x) | (f2bf_u(b.y) << 16));
  o.w = (int)(f2bf_u(b.z) | (f2bf_u(b.w) << 16));
  *((i32x4*)d + off) = o;
}

// ---------------- in-place RoPE on K only (Q roped inside attn) ----------------
__global__ __launch_bounds__(256) void rope_k_kernel(u16* __restrict__ Kb,
                                                     const float* __restrict__ cs,
                                                     const float* __restrict__ sn) {
  int t = blockIdx.x * 256 + threadIdx.x;  // S*4*16 threads
  int d0 = (t & 15) * 4;
  int r = t >> 4;
  int h = r & 3, s = r >> 2;
  u16* p = Kb + (size_t)s * 512 + h * 128 + d0;
  f32x4 c = *(const f32x4*)&cs[(s << 6) | d0];
  f32x4 si = *(const f32x4*)&sn[(s << 6) | d0];
  u16x4 a = *(u16x4*)p, b = *(u16x4*)(p + 64);
  u16x4 oa, ob;
#pragma unroll
  for (int j = 0; j < 4; ++j) {
    float x1 = bf2f(a[j]), x2 = bf2f(b[j]);
    oa[j] = (u16)f2bf_u(x1 * c[j] - x2 * si[j]);
    ob[j] = (u16)f2bf_u(x2 * c[j] + x1 * si[j]);
  }
  *(u16x4*)p = oa;
  *(u16x4*)(p + 64) = ob;
}

// ---------------- fused QKV GEMM: X[4096x2048] x {Wq,Wk,Wv}^T ----------------
__global__ __launch_bounds__(256) void qkv_gemm_kernel(
    const u16* __restrict__ A, const u16* __restrict__ Wq,
    const u16* __restrict__ Wk, const u16* __restrict__ Wv,
    u16* __restrict__ Qb, u16* __restrict__ Kb, u16* __restrict__ Vt) {
  __shared__ __attribute__((aligned(16))) u16 sA[128 * 64];
  __shared__ __attribute__((aligned(16))) u16 sB[128 * 64];
  const int lane = threadIdx.x & 63;
  const int w = threadIdx.x >> 6;
  const int g = lane >> 4, ln = lane & 15;
  const int K = HID;

  int wgid = blockIdx.x;                 // 768
  wgid = (wgid & 7) * 96 + (wgid >> 3);  // bijective XCD swizzle
  const int brow = (wgid / 24) * 128;
  const int bcol = (wgid % 24) * 128;

  const u16* B;
  u16* out;
  int bc, mode, N;
  if (bcol < 2048)      { B = Wq; out = Qb; bc = bcol;        N = 2048; mode = 0; }
  else if (bcol < 2560) { B = Wk; out = Kb; bc = bcol - 2048; N = 512;  mode = 0; }
  else                  { B = Wv; out = Vt; bc = bcol - 2560; N = 512;  mode = 1; }

  const int wr = (w >> 1) * 64, wc = (w & 1) * 64;
  f32x4 acc[4][4] = {};

  const int sr = w * 32 + (lane >> 3);
  const int scol = (lane & 7) * 8;
  const u16* Abase = A + (size_t)(brow + sr) * K + scol;
  const u16* Bbase = B + (size_t)(bc + sr) * K + scol;
  u16* sAdst = &sA[w * 2048];
  u16* sBdst = &sB[w * 2048];

  for (int k0 = 0; k0 < K; k0 += 64) {
    __syncthreads();
#pragma unroll
    for (int i = 0; i < 4; ++i) {
      gload_lds16(Abase + (size_t)i * 8 * K + k0, sAdst + i * 512);
      gload_lds16(Bbase + (size_t)i * 8 * K + k0, sBdst + i * 512);
    }
    __syncthreads();
#pragma unroll
    for (int kk = 0; kk < 2; ++kk) {
      i32x4 af[4], bfr[4];
#pragma unroll
      for (int m = 0; m < 4; ++m)
        af[m] = *(const i32x4*)&sA[(wr + m * 16 + ln) * 64 + kk * 32 + g * 8];
#pragma unroll
      for (int n = 0; n < 4; ++n)
        bfr[n] = *(const i32x4*)&sB[(wc + n * 16 + ln) * 64 + kk * 32 + g * 8];
#pragma unroll
      for (int m = 0; m < 4; ++m)
#pragma unroll
        for (int n = 0; n < 4; ++n) mfma16(acc[m][n], af[m], bfr[n]);
    }
  }

  const int orow0 = brow + wr + g * 4;
  const int ocol0 = bc + wc + ln;
#pragma unroll
  for (int m = 0; m < 4; ++m)
#pragma unroll
    for (int n = 0; n < 4; ++n)
#pragma unroll
      for (int j = 0; j < 4; ++j) {
        int row = orow0 + m * 16 + j;
        int col = ocol0 + n * 16;
        float v = acc[m][n][j];
        if (mode == 0) {
          out[(size_t)row * N + col] = (u16)f2bf_u(v);
        } else {
          int d = col & 127, kvh = col >> 7;
          int T = row >> 5, ks = row & 31;
          int tt = ks >> 4, gg = (ks >> 2) & 3, e = (tt << 2) | (ks & 3);
          size_t idx = (size_t)kvh * S_LEN * 128 + (size_t)T * 4096 +
                       (size_t)d * 32 + ((size_t)(gg ^ ((d >> 1) & 3)) << 3) + e;
          out[idx] = (u16)f2bf_u(v);
        }
      }
}

// ---------------- O-projection GEMM: fp32 out ----------------
__global__ __launch_bounds__(256) void gemm_o_kernel(const u16* __restrict__ A,
                                                     const u16* __restrict__ B,
                                                     float* __restrict__ Cv,
                                                     int K, int N) {
  __shared__ __attribute__((aligned(16))) u16 sA[128 * 64];
  __shared__ __attribute__((aligned(16))) u16 sB[128 * 64];
  const int lane = threadIdx.x & 63;
  const int w = threadIdx.x >> 6;
  const int g = lane >> 4, ln = lane & 15;

  int wgid = blockIdx.y * gridDim.x + blockIdx.x;
  const int nwg = gridDim.x * gridDim.y;
  wgid = (wgid & 7) * (nwg >> 3) + (wgid >> 3);
  const int brow = (wgid / gridDim.x) * 128;
  const int bcol = (wgid % gridDim.x) * 128;
  const int wr = (w >> 1) * 64, wc = (w & 1) * 64;

  f32x4 acc[4][4] = {};

  const int sr = w * 32 + (lane >> 3);
  const int scol = (lane & 7) * 8;
  const u16* Abase = A + (size_t)(brow + sr) * K + scol;
  const u16* Bbase = B + (size_t)(bcol + sr) * K + scol;
  u16* sAdst = &sA[w * 2048];
  u16* sBdst = &sB[w * 2048];

  for (int k0 = 0; k0 < K; k0 += 64) {
    __syncthreads();
#pragma unroll
    for (int i = 0; i < 4; ++i) {
      gload_lds16(Abase + (size_t)i * 8 * K + k0, sAdst + i * 512);
      gload_lds16(Bbase + (size_t)i * 8 * K + k0, sBdst + i * 512);
    }
    __syncthreads();
#pragma unroll
    for (int kk = 0; kk < 2; ++kk) {
      i32x4 af[4], bfr[4];
#pragma unroll
      for (int m = 0; m < 4; ++m)
        af[m] = *(const i32x4*)&sA[(wr + m * 16 + ln) * 64 + kk * 32 + g * 8];
#pragma unroll
      for (int n = 0; n < 4; ++n)
        bfr[n] = *(const i32x4*)&sB[(wc + n * 16 + ln) * 64 + kk * 32 + g * 8];
#pragma unroll
      for (int m = 0; m < 4; ++m)
#pragma unroll
        for (int n = 0; n < 4; ++n) mfma16(acc[m][n], af[m], bfr[n]);
    }
  }

  const int orow0 = brow + wr + g * 4;
  const int ocol0 = bcol + wc + ln;
#pragma unroll
  for (int m = 0; m < 4; ++m)
#pragma unroll
    for (int n = 0; n < 4; ++n)
#pragma unroll
      for (int j = 0; j < 4; ++j)
        Cv[(size_t)(orow0 + m * 16 + j) * N + ocol0 + n * 16] = acc[m][n][j];
}

// ---------------- flash attention: 4 independent waves / block ----------------
// r8-base structure (best measured). In-register Q-RoPE+scale; ballot-only
// defer-max common path (no cross-lane shfl unless rescale actually needed).
__global__ __launch_bounds__(256) void attn_kernel(const u16* __restrict__ Q,
                                                   const u16* __restrict__ Kb,
                                                   const u16* __restrict__ Vt,
                                                   const float* __restrict__ cs,
                                                   const float* __restrict__ sn,
                                                   u16* __restrict__ opart,
                                                   float* __restrict__ mpart,
                                                   float* __restrict__ lpart) {
  const int lane = threadIdx.x & 63;
  const int w = threadIdx.x >> 6;
  const int g = lane >> 4, ln = lane & 15;

  const int b = blockIdx.x;                 // 1024
  const int h = ((b & 7) << 1) | (w >> 1);  // 2 heads per XCD
  const int chunk = w & 1;
  const int gq = 127 - (b >> 3);            // heavy q-groups first
  const int kvh = h >> 2;
  const int qr0 = gq * 32;

  const float SC2 = 0.088388347648318447f * 1.4426950408889634f;  // 1/sqrt(d)*log2e

  // load raw Q fragments, apply RoPE + scale in registers
  i32x4 aq[2][4];
#pragma unroll
  for (int qf = 0; qf < 2; ++qf) {
    const int s = qr0 + qf * 16 + ln;
    const u16* qp = Q + (size_t)s * HID + h * 128 + g * 8;
#pragma unroll
    for (int c = 0; c < 4; ++c) aq[qf][c] = *(const i32x4*)(qp + c * 32);
#pragma unroll
    for (int cp = 0; cp < 2; ++cp) {
      const float* cbase = &cs[(s << 6) + cp * 32 + g * 8];
      const float* sbase = &sn[(s << 6) + cp * 32 + g * 8];
      f32x4 c0 = *(const f32x4*)cbase, c1 = *(const f32x4*)(cbase + 4);
      f32x4 s0 = *(const f32x4*)sbase, s1 = *(const f32x4*)(sbase + 4);
      i32x4 lo = aq[qf][cp], hi = aq[qf][cp + 2];
      i32x4 nlo, nhi;
#pragma unroll
      for (int wi = 0; wi < 4; ++wi) {
        u32 lw = (u32)lo[wi], hw = (u32)hi[wi];
        float x1a = bf2f((u16)lw), x1b = bf2f((u16)(lw >> 16));
        float x2a = bf2f((u16)hw), x2b = bf2f((u16)(hw >> 16));
        float ca = (wi * 2 < 4) ? c0[(wi * 2) & 3] : c1[(wi * 2) & 3];
        float cb = (wi * 2 + 1 < 4) ? c0[(wi * 2 + 1) & 3] : c1[(wi * 2 + 1) & 3];
        float sa = (wi * 2 < 4) ? s0[(wi * 2) & 3] : s1[(wi * 2) & 3];
        float sb = (wi * 2 + 1 < 4) ? s0[(wi * 2 + 1) & 3] : s1[(wi * 2 + 1) & 3];
        float o1a = (x1a * ca - x2a * sa) * SC2;
        float o2a = (x2a * ca + x1a * sa) * SC2;
        float o1b = (x1b * cb - x2b * sb) * SC2;
        float o2b = (x2b * cb + x1b * sb) * SC2;
        nlo[wi] = (int)(f2bf_u(o1a) | (f2bf_u(o1b) << 16));
        nhi[wi] = (int)(f2bf_u(o2a) | (f2bf_u(o2b) << 16));
      }
      aq[qf][cp] = nlo;
      aq[qf][cp + 2] = nhi;
    }
  }

  f32x4 oacc[2][8] = {};
  float mrun[2] = {-1e30f, -1e30f};
  float lrun[2] = {0.f, 0.f};  // per-lane partial; cross-lane reduce at end

  int lo = qr0 - (WIN - 1);
  if (lo < 0) lo = 0;
  lo &= ~31;
  const int nt_full = ((qr0 + 32) - lo) >> 5;
  const int nt0 = nt_full >> 1;
  const int lo_c = lo + (chunk ? nt0 * 32 : 0);
  const int nt = chunk ? nt_full - nt0 : nt0;

  const u16* kptr = Kb + (size_t)(lo_c + ln) * 512 + kvh * 128 + g * 8;
  const int vswz = (g ^ ((ln >> 1) & 3)) << 3;
  const u16* vptr = Vt + (size_t)kvh * S_LEN * 128 +
                    (size_t)(lo_c >> 5) * 4096 + ln * 32 + vswz;

  i32x4 kf[2][4], vf[8];
  if (nt > 0) {
#pragma unroll
    for (int tt = 0; tt < 2; ++tt)
#pragma unroll
      for (int c = 0; c < 4; ++c)
        kf[tt][c] = *(const i32x4*)(kptr + tt * 8192 + c * 32);
#pragma unroll
    for (int nf = 0; nf < 8; ++nf) vf[nf] = *(const i32x4*)(vptr + nf * 512);
  }

  for (int it = 0; it < nt; ++it) {
    const int kb = lo_c + it * 32;
    const bool more = (it + 1 < nt);

    // S = K Q^T (swapped): lane q-col=qf*16+ln, k=kb+t*16+g*4+j; exp2 domain
    f32x4 sc[2][2] = {};
    __builtin_amdgcn_s_setprio(1);
#pragma unroll
    for (int c = 0; c < 4; ++c) {
      mfma16(sc[0][0], kf[0][c], aq[0][c]);
      mfma16(sc[0][1], kf[1][c], aq[0][c]);
      mfma16(sc[1][0], kf[0][c], aq[1][c]);
      mfma16(sc[1][1], kf[1][c], aq[1][c]);
    }
    __builtin_amdgcn_s_setprio(0);

    if (more) {
      kptr += 32 * 512;
#pragma unroll
      for (int tt = 0; tt < 2; ++tt)
#pragma unroll
        for (int c = 0; c < 4; ++c)
          kf[tt][c] = *(const i32x4*)(kptr + tt * 8192 + c * 32);
    }

    float p[2][8], mxl[2];
    const bool interior = (kb + 31 <= qr0) && (qr0 + 31 - kb < WIN);
#pragma unroll
    for (int qf = 0; qf < 2; ++qf) {
      if (interior) {
#pragma unroll
        for (int j = 0; j < 4; ++j) {
          p[qf][j] = sc[qf][0][j];
          p[qf][4 + j] = sc[qf][1][j];
        }
      } else {
        const float NEG = -__builtin_inff();
        const int q = qr0 + qf * 16 + ln;
#pragma unroll
        for (int tt = 0; tt < 2; ++tt)
#pragma unroll
          for (int j = 0; j < 4; ++j) {
            int k = kb + tt * 16 + g * 4 + j;
            p[qf][tt * 4 + j] = (k <= q && q - k < WIN) ? sc[qf][tt][j] : NEG;
          }
      }
      // per-lane max only (no cross-lane on common path)
      float x0 = fmaxf(fmaxf(p[qf][0], p[qf][1]), p[qf][2]);
      float x1 = fmaxf(fmaxf(p[qf][3], p[qf][4]), p[qf][5]);
      float x2 = fmaxf(fmaxf(p[qf][6], p[qf][7]), x0);
      mxl[qf] = fmaxf(x1, x2);
    }

    // defer-max: ballot aggregates across all lanes/rows; shfl only when needed
    const bool okl =
        (mxl[0] - mrun[0] <= 11.f) && (mxl[1] - mrun[1] <= 11.f);
    if (!__all(okl)) {
#pragma unroll
      for (int qf = 0; qf < 2; ++qf) {
        float m = mxl[qf];
        m = fmaxf(m, __shfl_xor(m, 16));
        m = fmaxf(m, __shfl_xor(m, 32));
        float mnew = fmaxf(mrun[qf], m);
        float corr = exp2x(mrun[qf] - mnew);
        mrun[qf] = mnew;
        lrun[qf] *= corr;
        f32x4 cv;
#pragma unroll
        for (int j = 0; j < 4; ++j) cv[j] = __shfl(corr, g * 4 + j);
#pragma unroll
        for (int nf = 0; nf < 8; ++nf)
#pragma unroll
          for (int j = 0; j < 4; ++j) oacc[qf][nf][j] *= cv[j];
      }
    }

    i32x4 pa[2];
#pragma unroll
    for (int qf = 0; qf < 2; ++qf) {
      f32x8 pv;
#pragma unroll
      for (int e = 0; e < 8; ++e) pv[e] = exp2x(p[qf][e] - mrun[qf]);
      float rs = ((pv[0] + pv[1]) + (pv[2] + pv[3])) +
                 ((pv[4] + pv[5]) + (pv[6] + pv[7]));
      lrun[qf] += rs;
      bf16x8 pb = __builtin_convertvector(pv, bf16x8);
      pa[qf] = __builtin_bit_cast(i32x4, pb);
    }

    __builtin_amdgcn_s_setprio(1);
#pragma unroll
    for (int nf = 0; nf < 8; ++nf) {
      mfma16(oacc[0][nf], pa[0], vf[nf]);
      mfma16(oacc[1][nf], pa[1], vf[nf]);
    }
    __builtin_amdgcn_s_setprio(0);

    if (more) {
      vptr += 4096;
#pragma unroll
      for (int nf = 0; nf < 8; ++nf) vf[nf] = *(const i32x4*)(vptr + nf * 512);
    }
  }

  // finish deferred cross-lane l reduction
#pragma unroll
  for (int qf = 0; qf < 2; ++qf) {
    float l = lrun[qf];
    l += __shfl_xor(l, 16);
    l += __shfl_xor(l, 32);
    lrun[qf] = l;
  }

  const size_t pb = ((size_t)chunk * 16 + h) * S_LEN;
#pragma unroll
  for (int qf = 0; qf < 2; ++qf) {
    if (g == 0) {
      mpart[pb + qr0 + qf * 16 + ln] = mrun[qf];  // log2-domain
      lpart[pb + qr0 + qf * 16 + ln] = lrun[qf];
    }
    u16* aop = opart + (pb + qr0 + qf * 16 + g * 4) * 128 + ln;
#pragma unroll
    for (int j = 0; j < 4; ++j)
#pragma unroll
      for (int nf = 0; nf < 8; ++nf)
        aop[(size_t)j * 128 + nf * 16] = (u16)f2bf_u(oacc[qf][nf][j]);
  }
}

// ---------------- combine partials (log2-domain m) -> AO bf16 ----------------
__global__ __launch_bounds__(256) void attn_combine_kernel(
    const u16* __restrict__ opart, const float* __restrict__ mpart,
    const float* __restrict__ lpart, u16* __restrict__ AO) {
  int t = blockIdx.x * 256 + threadIdx.x;  // 16*4096*16 threads
  int d0 = (t & 15) * 8;
  int rh = t >> 4;
  int row = rh & (S_LEN - 1);
  int h = rh >> 12;
  size_t i0 = (size_t)h * S_LEN + row;
  size_t i1 = i0 + (size_t)16 * S_LEN;
  float m0 = mpart[i0], m1 = mpart[i1];
  float l0 = lpart[i0], l1 = lpart[i1];
  float m = fmaxf(m0, m1);
  float w0 = exp2x(m0 - m), w1 = exp2x(m1 - m);
  float inv = 1.f / (l0 * w0 + l1 * w1);
  w0 *= inv;
  w1 *= inv;
  i32x4 v0 = *(const i32x4*)(opart + i0 * 128 + d0);
  i32x4 v1 = *(const i32x4*)(opart + i1 * 128 + d0);
  i32x4 ov;
#pragma unroll
  for (int j = 0; j < 4; ++j) {
    u32 a = ((u32)v0[j]), b = ((u32)v1[j]);
    float x = bf2f((u16)a) * w0 + bf2f((u16)b) * w1;
    float y = bf2f((u16)(a >> 16)) * w0 + bf2f((u16)(b >> 16)) * w1;
    ov[j] = (int)(f2bf_u(x) | (f2bf_u(y) << 16));
  }
  *(i32x4*)(AO + (size_t)row * HID + h * 128 + d0) = ov;
}

// ---------------- orchestration ----------------
extern "C" void kernel_launch(void* const* d_in, const int* in_sizes, int n_in,
                              void* d_out, int out_size, void* d_ws, size_t ws_size,
                              hipStream_t stream) {
  const float* hx = (const float*)d_in[0];
  const float* qw = (const float*)d_in[1];
  const float* kw = (const float*)d_in[2];
  const float* vw = (const float*)d_in[3];
  const float* ow = (const float*)d_in[4];

  char* p = (char*)d_ws;
  u16* Xb = (u16*)p; p += (size_t)S_LEN * HID * 2;
  u16* Wq = (u16*)p; p += (size_t)HID * HID * 2;
  u16* Wk = (u16*)p; p += (size_t)512 * HID * 2;
  u16* Wv = (u16*)p; p += (size_t)512 * HID * 2;
  u16* Wo = (u16*)p; p += (size_t)HID * HID * 2;
  u16* Qb = (u16*)p; p += (size_t)S_LEN * HID * 2;
  u16* Kb = (u16*)p; p += (size_t)S_LEN * 512 * 2;
  u16* Vt = (u16*)p; p += (size_t)S_LEN * 512 * 2;
  u16* AO = (u16*)p; p += (size_t)S_LEN * HID * 2;
  float* cs = (float*)p; p += (size_t)S_LEN * 64 * 4;
  float* sn = (float*)p; p += (size_t)S_LEN * 64 * 4;
  u16* Opart = (u16*)p; p += (size_t)2 * 16 * S_LEN * 128 * 2;  // 32 MB
  float* Mpart = (float*)p; p += (size_t)2 * 16 * S_LEN * 4;
  float* Lpart = (float*)p; p += (size_t)2 * 16 * S_LEN * 4;

  cvt_all_kernel<<<(CVT_B5 + 255) / 256, 256, 0, stream>>>(
      hx, qw, kw, vw, ow, Xb, Wq, Wk, Wv, Wo, cs, sn);

  qkv_gemm_kernel<<<768, 256, 0, stream>>>(Xb, Wq, Wk, Wv, Qb, Kb, Vt);

  rope_k_kernel<<<S_LEN * 4 * 16 / 256, 256, 0, stream>>>(Kb, cs, sn);

  attn_kernel<<<1024, 256, 0, stream>>>(Qb, Kb, Vt, cs, sn, Opart, Mpart,
                                        Lpart);
  attn_combine_kernel<<<S_LEN * 16 * 16 / 256, 256, 0, stream>>>(Opart, Mpart,
                                                                 Lpart, AO);

  gemm_o_kernel<<<dim3(16, 32), 256, 0, stream>>>(AO, Wo, (float*)d_out, HID,
                                                  HID);
}

// Round 15
// 297.926 us; speedup vs baseline: 1.0910x; 1.0858x over previous
//
#include <hip/hip_runtime.h>
#include <stdint.h>

typedef unsigned short u16;
typedef unsigned int u32;
typedef float f32x4 __attribute__((ext_vector_type(4)));
typedef float f32x8 __attribute__((ext_vector_type(8)));
typedef int   i32x4 __attribute__((ext_vector_type(4)));
typedef __bf16 bf16x8 __attribute__((ext_vector_type(8)));
typedef u16 u16x4 __attribute__((ext_vector_type(4)));

constexpr int S_LEN = 4096;
constexpr int HID   = 2048;
constexpr int WIN   = 2048;

__device__ __forceinline__ u32 f2bf_u(float f) {
  u32 u = __builtin_bit_cast(u32, f);
  return (u + 0x7fffu + ((u >> 16) & 1u)) >> 16;
}
__device__ __forceinline__ float bf2f(u16 u) {
  return __builtin_bit_cast(float, ((u32)u) << 16);
}
__device__ __forceinline__ float exp2x(float x) {
#if __has_builtin(__builtin_amdgcn_exp2f)
  return __builtin_amdgcn_exp2f(x);
#else
  return exp2f(x);
#endif
}
__device__ __forceinline__ void mfma16(f32x4& acc, i32x4 a, i32x4 b) {
  acc = __builtin_amdgcn_mfma_f32_16x16x32_bf16(
      __builtin_bit_cast(bf16x8, a), __builtin_bit_cast(bf16x8, b), acc, 0, 0, 0);
}
__device__ __forceinline__ void gload_lds16(const u16* g, u16* l) {
  __builtin_amdgcn_global_load_lds((const __attribute__((address_space(1))) u32*)g,
                                   (__attribute__((address_space(3))) u32*)l, 16, 0, 0);
}

// -------- fused fp32 -> bf16 convert (5 tensors) + RoPE cos/sin table -------
constexpr int CVT_B0 = 1048576;            // X
constexpr int CVT_B1 = CVT_B0 + 524288;    // +Wq
constexpr int CVT_B2 = CVT_B1 + 131072;    // +Wk
constexpr int CVT_B3 = CVT_B2 + 131072;    // +Wv
constexpr int CVT_B4 = CVT_B3 + 524288;    // +Wo
constexpr int CVT_B5 = CVT_B4 + 32768;     // +rope table (S*64/8 threads)

__global__ __launch_bounds__(256) void cvt_all_kernel(
    const float* __restrict__ s0, const float* __restrict__ s1,
    const float* __restrict__ s2, const float* __restrict__ s3,
    const float* __restrict__ s4, u16* __restrict__ d0, u16* __restrict__ d1,
    u16* __restrict__ d2, u16* __restrict__ d3, u16* __restrict__ d4,
    float* __restrict__ cs, float* __restrict__ sn) {
  int t = blockIdx.x * 256 + threadIdx.x;
  if (t >= CVT_B4) {
    if (t >= CVT_B5) return;
    int e = (t - CVT_B4) * 8;
    int d = e & 63, s = e >> 6;
#pragma unroll
    for (int j = 0; j < 8; ++j) {
      float inv = exp2f(-(float)(d + j) * 0.20762050593046014f);  // log2(1e4)/64
      float f = (float)s * inv;
      cs[e + j] = cosf(f);
      sn[e + j] = sinf(f);
    }
    return;
  }
  const float* s;
  u16* d;
  int off;
  if (t < CVT_B0) { s = s0; d = d0; off = t; }
  else if (t < CVT_B1) { s = s1; d = d1; off = t - CVT_B0; }
  else if (t < CVT_B2) { s = s2; d = d2; off = t - CVT_B1; }
  else if (t < CVT_B3) { s = s3; d = d3; off = t - CVT_B2; }
  else { s = s4; d = d4; off = t - CVT_B3; }
  const f32x4* sp = (const f32x4*)s + (size_t)off * 2;
  f32x4 a = sp[0], b = sp[1];
  i32x4 o;
  o.x = (int)(f2bf_u(a.x) | (f2bf_u(a.y) << 16));
  o.y = (int)(f2bf_u(a.z) | (f2bf_u(a.w) << 16));
  o.z = (int)(f2bf_u(b.x) | (f2bf_u(b.y) << 16));
  o.w = (int)(f2bf_u(b.z) | (f2bf_u(b.w) << 16));
  *((i32x4*)d + off) = o;
}

// ---------------- fused in-place RoPE on Q (scaled) and K ----------------
// Q additionally multiplied by 1/sqrt(128)*log2(e) (softmax runs in exp2 domain)
__global__ __launch_bounds__(256) void rope_qk_kernel(u16* __restrict__ Qb,
                                                      u16* __restrict__ Kb,
                                                      const float* __restrict__ cs,
                                                      const float* __restrict__ sn) {
  const float SC2 = 0.088388347648318447f * 1.4426950408889634f;
  int t = blockIdx.x * 256 + threadIdx.x;  // S*(16+4)*16 threads
  int d0 = (t & 15) * 4;
  int r = t >> 4;
  u16* p;
  int s;
  float qs;
  if (r < S_LEN * 16) {
    int h = r & 15; s = r >> 4;
    p = Qb + (size_t)s * HID + h * 128 + d0;
    qs = SC2;
  } else {
    int r2 = r - S_LEN * 16;
    int h = r2 & 3; s = r2 >> 2;
    p = Kb + (size_t)s * 512 + h * 128 + d0;
    qs = 1.f;
  }
  f32x4 c = *(const f32x4*)&cs[(s << 6) | d0];
  f32x4 si = *(const f32x4*)&sn[(s << 6) | d0];
  u16x4 a = *(u16x4*)p, b = *(u16x4*)(p + 64);
  u16x4 oa, ob;
#pragma unroll
  for (int j = 0; j < 4; ++j) {
    float x1 = bf2f(a[j]), x2 = bf2f(b[j]);
    oa[j] = (u16)f2bf_u((x1 * c[j] - x2 * si[j]) * qs);
    ob[j] = (u16)f2bf_u((x2 * c[j] + x1 * si[j]) * qs);
  }
  *(u16x4*)p = oa;
  *(u16x4*)(p + 64) = ob;
}

// ============ 256x128 GEMM core: counted-vmcnt pipeline + LDS swizzle ========
// C[..][N] = A[M][2048] x B[N][2048]^T. 512 thr = 8 waves (4 row x 2 col).
// BK=64; 2 LDS buffers (96 KB); per K-tile: compute -> barrier ->
// STAGE(kt+2 into consumed buf) -> vmcnt(6) -> barrier. Never drains to 0.
// LDS swizzle: 16B-slot ^= (row&7) on both staging source and frag reads.
__device__ __forceinline__ void gemm256_core(const u16* __restrict__ A_,
                                             const u16* __restrict__ Bm_,
                                             int brow_, int bc_,
                                             f32x4 (&acc)[4][4], int& orow0,
                                             int& ocol0) {
  __shared__ __attribute__((aligned(16))) u16 sA[2][256 * 64];
  __shared__ __attribute__((aligned(16))) u16 sB[2][128 * 64];
  const int t = threadIdx.x;
  const int lane = t & 63;
  const int w = t >> 6;
  const int g = lane >> 4, ln = lane & 15;
  const int wm = w >> 1, wn = w & 1;
  const int trow = t >> 3, tslot = t & 7;
  const int sslot = tslot ^ (trow & 7);
  const u16* Abase = A_ + (size_t)(brow_ + trow) * 2048 + sslot * 8;
  const u16* Bbase = Bm_ + (size_t)(bc_ + trow) * 2048 + sslot * 8;

#define STAGE6(buf, kt)                                                        \
  {                                                                            \
    const int _k0 = (kt) * 64;                                                 \
    _Pragma("unroll") for (int a2 = 0; a2 < 4; ++a2)                           \
        gload_lds16(Abase + (size_t)a2 * 64 * 2048 + _k0,                      \
                    &sA[buf][a2 * 4096 + t * 8]);                              \
    _Pragma("unroll") for (int b2 = 0; b2 < 2; ++b2)                           \
        gload_lds16(Bbase + (size_t)b2 * 64 * 2048 + _k0,                      \
                    &sB[buf][b2 * 4096 + t * 8]);                              \
  }

  STAGE6(0, 0);
  STAGE6(1, 1);
  asm volatile("s_waitcnt vmcnt(6)" ::: "memory");
  __builtin_amdgcn_s_barrier();
  int cur = 0;
  for (int kt = 0; kt < 32; ++kt) {
    i32x4 bfr[4][2];
#pragma unroll
    for (int n = 0; n < 4; ++n) {
      const int row = wn * 64 + n * 16 + ln;
      const int sw = row & 7;
      bfr[n][0] = *(const i32x4*)&sB[cur][row * 64 + ((g ^ sw) << 3)];
      bfr[n][1] = *(const i32x4*)&sB[cur][row * 64 + (((4 | g) ^ sw) << 3)];
    }
    __builtin_amdgcn_s_setprio(1);
#pragma unroll
    for (int m = 0; m < 4; ++m) {
      const int row = wm * 64 + m * 16 + ln;
      const int sw = row & 7;
      i32x4 a0 = *(const i32x4*)&sA[cur][row * 64 + ((g ^ sw) << 3)];
      i32x4 a1 = *(const i32x4*)&sA[cur][row * 64 + (((4 | g) ^ sw) << 3)];
#pragma unroll
      for (int n = 0; n < 4; ++n) {
        mfma16(acc[m][n], a0, bfr[n][0]);
        mfma16(acc[m][n], a1, bfr[n][1]);
      }
    }
    __builtin_amdgcn_s_setprio(0);
    __builtin_amdgcn_s_barrier();
    if (kt + 2 < 32) {
      STAGE6(cur, kt + 2);
      asm volatile("s_waitcnt vmcnt(6)" ::: "memory");
    } else if (kt + 1 < 32) {
      asm volatile("s_waitcnt vmcnt(0)" ::: "memory");
    }
    __builtin_amdgcn_s_barrier();
    cur ^= 1;
  }
#undef STAGE6
  orow0 = brow_ + wm * 64 + g * 4;
  ocol0 = bc_ + wn * 64 + ln;
}

// ---------------- fused QKV GEMM (256x128 tiles, 384 blocks) ----------------
// col-tiles 0-15 -> Qb; 16-19 -> Kb; 20-23 -> Vt (tiled attn layout)
__global__ __launch_bounds__(512) void qkv256_kernel(
    const u16* __restrict__ A, const u16* __restrict__ Wq,
    const u16* __restrict__ Wk, const u16* __restrict__ Wv,
    u16* __restrict__ Qb, u16* __restrict__ Kb, u16* __restrict__ Vt) {
  int wgid = blockIdx.x;                 // 384
  wgid = (wgid & 7) * 48 + (wgid >> 3);  // bijective XCD swizzle
  const int brow = (wgid / 24) * 256;
  const int bcol = (wgid % 24) * 128;
  const u16* Bm;
  u16* out;
  int bc, mode, N;
  if (bcol < 2048)      { Bm = Wq; out = Qb; bc = bcol;        N = 2048; mode = 0; }
  else if (bcol < 2560) { Bm = Wk; out = Kb; bc = bcol - 2048; N = 512;  mode = 0; }
  else                  { Bm = Wv; out = Vt; bc = bcol - 2560; N = 512;  mode = 1; }

  f32x4 acc[4][4] = {};
  int orow0, ocol0;
  gemm256_core(A, Bm, brow, bc, acc, orow0, ocol0);

#pragma unroll
  for (int m = 0; m < 4; ++m)
#pragma unroll
    for (int n = 0; n < 4; ++n)
#pragma unroll
      for (int j = 0; j < 4; ++j) {
        int row = orow0 + m * 16 + j;
        int col = ocol0 + n * 16;
        float v = acc[m][n][j];
        if (mode == 0) {
          out[(size_t)row * N + col] = (u16)f2bf_u(v);
        } else {
          int d = col & 127, kvh = col >> 7;
          int T = row >> 5, ks = row & 31;
          int tt = ks >> 4, gg = (ks >> 2) & 3, e = (tt << 2) | (ks & 3);
          size_t idx = (size_t)kvh * S_LEN * 128 + (size_t)T * 4096 +
                       (size_t)d * 32 + ((size_t)(gg ^ ((d >> 1) & 3)) << 3) + e;
          out[idx] = (u16)f2bf_u(v);
        }
      }
}

// ---------------- O-projection GEMM (256x128 tiles, 256 blocks, fp32 out) ----
__global__ __launch_bounds__(512) void o256_kernel(const u16* __restrict__ A,
                                                   const u16* __restrict__ Bw,
                                                   float* __restrict__ Cv) {
  int wgid = blockIdx.x;                 // 256
  wgid = (wgid & 7) * 32 + (wgid >> 3);  // bijective XCD swizzle
  const int brow = (wgid / 16) * 256;
  const int bcol = (wgid % 16) * 128;

  f32x4 acc[4][4] = {};
  int orow0, ocol0;
  gemm256_core(A, Bw, brow, bcol, acc, orow0, ocol0);

#pragma unroll
  for (int m = 0; m < 4; ++m)
#pragma unroll
    for (int n = 0; n < 4; ++n)
#pragma unroll
      for (int j = 0; j < 4; ++j)
        Cv[(size_t)(orow0 + m * 16 + j) * 2048 + ocol0 + n * 16] = acc[m][n][j];
}

// ---------------- flash attention: barrier-free wave-flash (r8-best) --------
// 1 wave per block; 32 q-rows; 2-way KV-split; K/V global->regs; exp2-domain.
__global__ __launch_bounds__(64) void attn_kernel(const u16* __restrict__ Q,
                                                  const u16* __restrict__ Kb,
                                                  const u16* __restrict__ Vt,
                                                  u16* __restrict__ opart,
                                                  float* __restrict__ mpart,
                                                  float* __restrict__ lpart) {
  const int lane = threadIdx.x;
  const int g = lane >> 4, ln = lane & 15;

  const int o = blockIdx.x;                     // 4096
  const int wgid = ((o & 7) << 9) | (o >> 3);   // XCD-pin: 2 heads per XCD
  const int h = wgid >> 8;
  const int idx = wgid & 255;
  const int chunk = idx & 1;
  const int gq = 127 - (idx >> 1);              // heavy q-groups first
  const int kvh = h >> 2;
  const int qr0 = gq * 32;

  i32x4 aq[2][4];
#pragma unroll
  for (int qf = 0; qf < 2; ++qf) {
    const u16* qp = Q + (size_t)(qr0 + qf * 16 + ln) * HID + h * 128 + g * 8;
#pragma unroll
    for (int c = 0; c < 4; ++c) aq[qf][c] = *(const i32x4*)(qp + c * 32);
  }

  f32x4 oacc[2][8] = {};
  float mrun[2] = {-1e30f, -1e30f};
  float lrun[2] = {0.f, 0.f};  // per-lane partial; cross-lane reduce at end

  int lo = qr0 - (WIN - 1);
  if (lo < 0) lo = 0;
  lo &= ~31;
  const int nt_full = ((qr0 + 32) - lo) >> 5;
  const int nt0 = nt_full >> 1;
  const int lo_c = lo + (chunk ? nt0 * 32 : 0);
  const int nt = chunk ? nt_full - nt0 : nt0;

  const u16* kptr = Kb + (size_t)(lo_c + ln) * 512 + kvh * 128 + g * 8;
  const int vswz = (g ^ ((ln >> 1) & 3)) << 3;
  const u16* vptr = Vt + (size_t)kvh * S_LEN * 128 +
                    (size_t)(lo_c >> 5) * 4096 + ln * 32 + vswz;

  i32x4 kf[2][4], vf[8];
  if (nt > 0) {
#pragma unroll
    for (int tt = 0; tt < 2; ++tt)
#pragma unroll
      for (int c = 0; c < 4; ++c)
        kf[tt][c] = *(const i32x4*)(kptr + tt * 8192 + c * 32);
#pragma unroll
    for (int nf = 0; nf < 8; ++nf) vf[nf] = *(const i32x4*)(vptr + nf * 512);
  }

  for (int it = 0; it < nt; ++it) {
    const int kb = lo_c + it * 32;
    const bool more = (it + 1 < nt);

    f32x4 sc[2][2] = {};
    __builtin_amdgcn_s_setprio(1);
#pragma unroll
    for (int c = 0; c < 4; ++c) {
      mfma16(sc[0][0], kf[0][c], aq[0][c]);
      mfma16(sc[0][1], kf[1][c], aq[0][c]);
      mfma16(sc[1][0], kf[0][c], aq[1][c]);
      mfma16(sc[1][1], kf[1][c], aq[1][c]);
    }
    __builtin_amdgcn_s_setprio(0);

    if (more) {
      kptr += 32 * 512;
#pragma unroll
      for (int tt = 0; tt < 2; ++tt)
#pragma unroll
        for (int c = 0; c < 4; ++c)
          kf[tt][c] = *(const i32x4*)(kptr + tt * 8192 + c * 32);
    }

    float p[2][8];
    float mx[2];
    const bool interior = (kb + 31 <= qr0) && (qr0 + 31 - kb < WIN);
#pragma unroll
    for (int qf = 0; qf < 2; ++qf) {
      if (interior) {
#pragma unroll
        for (int j = 0; j < 4; ++j) {
          p[qf][j] = sc[qf][0][j];
          p[qf][4 + j] = sc[qf][1][j];
        }
      } else {
        const float NEG = -__builtin_inff();
        const int q = qr0 + qf * 16 + ln;
#pragma unroll
        for (int tt = 0; tt < 2; ++tt)
#pragma unroll
          for (int j = 0; j < 4; ++j) {
            int k = kb + tt * 16 + g * 4 + j;
            p[qf][tt * 4 + j] = (k <= q && q - k < WIN) ? sc[qf][tt][j] : NEG;
          }
      }
      float x0 = fmaxf(fmaxf(p[qf][0], p[qf][1]), p[qf][2]);
      float x1 = fmaxf(fmaxf(p[qf][3], p[qf][4]), p[qf][5]);
      float x2 = fmaxf(fmaxf(p[qf][6], p[qf][7]), x0);
      float m = fmaxf(x1, x2);
      m = fmaxf(m, __shfl_xor(m, 16));
      m = fmaxf(m, __shfl_xor(m, 32));
      mx[qf] = m;
    }

    float corr[2] = {1.f, 1.f};
    const bool noskip =
        !__all((mx[0] - mrun[0] <= 11.f) && (mx[1] - mrun[1] <= 11.f));
    if (noskip) {
#pragma unroll
      for (int qf = 0; qf < 2; ++qf) {
        float mnew = fmaxf(mrun[qf], mx[qf]);
        corr[qf] = exp2x(mrun[qf] - mnew);
        mrun[qf] = mnew;
        f32x4 cv;
#pragma unroll
        for (int j = 0; j < 4; ++j) cv[j] = __shfl(corr[qf], g * 4 + j);
#pragma unroll
        for (int nf = 0; nf < 8; ++nf)
#pragma unroll
          for (int j = 0; j < 4; ++j) oacc[qf][nf][j] *= cv[j];
      }
    }

    i32x4 pa[2];
#pragma unroll
    for (int qf = 0; qf < 2; ++qf) {
      f32x8 pv;
#pragma unroll
      for (int e = 0; e < 8; ++e) pv[e] = exp2x(p[qf][e] - mrun[qf]);
      float rs = ((pv[0] + pv[1]) + (pv[2] + pv[3])) +
                 ((pv[4] + pv[5]) + (pv[6] + pv[7]));
      lrun[qf] = lrun[qf] * corr[qf] + rs;
      bf16x8 pb = __builtin_convertvector(pv, bf16x8);
      pa[qf] = __builtin_bit_cast(i32x4, pb);
    }

    __builtin_amdgcn_s_setprio(1);
#pragma unroll
    for (int nf = 0; nf < 8; ++nf) {
      mfma16(oacc[0][nf], pa[0], vf[nf]);
      mfma16(oacc[1][nf], pa[1], vf[nf]);
    }
    __builtin_amdgcn_s_setprio(0);

    if (more) {
      vptr += 4096;
#pragma unroll
      for (int nf = 0; nf < 8; ++nf) vf[nf] = *(const i32x4*)(vptr + nf * 512);
    }
  }

#pragma unroll
  for (int qf = 0; qf < 2; ++qf) {
    float l = lrun[qf];
    l += __shfl_xor(l, 16);
    l += __shfl_xor(l, 32);
    lrun[qf] = l;
  }

  const size_t pb = ((size_t)chunk * 16 + h) * S_LEN;
#pragma unroll
  for (int qf = 0; qf < 2; ++qf) {
    if (g == 0) {
      mpart[pb + qr0 + qf * 16 + ln] = mrun[qf];  // log2-domain
      lpart[pb + qr0 + qf * 16 + ln] = lrun[qf];
    }
    u16* aop = opart + (pb + qr0 + qf * 16 + g * 4) * 128 + ln;
#pragma unroll
    for (int j = 0; j < 4; ++j)
#pragma unroll
      for (int nf = 0; nf < 8; ++nf)
        aop[(size_t)j * 128 + nf * 16] = (u16)f2bf_u(oacc[qf][nf][j]);
  }
}

// ---------------- combine partials (log2-domain m) -> AO bf16 ----------------
__global__ __launch_bounds__(256) void attn_combine_kernel(
    const u16* __restrict__ opart, const float* __restrict__ mpart,
    const float* __restrict__ lpart, u16* __restrict__ AO) {
  int t = blockIdx.x * 256 + threadIdx.x;  // 16*4096*16 threads
  int d0 = (t & 15) * 8;
  int rh = t >> 4;
  int row = rh & (S_LEN - 1);
  int h = rh >> 12;
  size_t i0 = (size_t)h * S_LEN + row;
  size_t i1 = i0 + (size_t)16 * S_LEN;
  float m0 = mpart[i0], m1 = mpart[i1];
  float l0 = lpart[i0], l1 = lpart[i1];
  float m = fmaxf(m0, m1);
  float w0 = exp2x(m0 - m), w1 = exp2x(m1 - m);
  float inv = 1.f / (l0 * w0 + l1 * w1);
  w0 *= inv;
  w1 *= inv;
  i32x4 v0 = *(const i32x4*)(opart + i0 * 128 + d0);
  i32x4 v1 = *(const i32x4*)(opart + i1 * 128 + d0);
  i32x4 ov;
#pragma unroll
  for (int j = 0; j < 4; ++j) {
    u32 a = ((u32)v0[j]), b = ((u32)v1[j]);
    float x = bf2f((u16)a) * w0 + bf2f((u16)b) * w1;
    float y = bf2f((u16)(a >> 16)) * w0 + bf2f((u16)(b >> 16)) * w1;
    ov[j] = (int)(f2bf_u(x) | (f2bf_u(y) << 16));
  }
  *(i32x4*)(AO + (size_t)row * HID + h * 128 + d0) = ov;
}

// ---------------- orchestration ----------------
extern "C" void kernel_launch(void* const* d_in, const int* in_sizes, int n_in,
                              void* d_out, int out_size, void* d_ws, size_t ws_size,
                              hipStream_t stream) {
  const float* hx = (const float*)d_in[0];
  const float* qw = (const float*)d_in[1];
  const float* kw = (const float*)d_in[2];
  const float* vw = (const float*)d_in[3];
  const float* ow = (const float*)d_in[4];

  char* p = (char*)d_ws;
  u16* Xb = (u16*)p; p += (size_t)S_LEN * HID * 2;
  u16* Wq = (u16*)p; p += (size_t)HID * HID * 2;
  u16* Wk = (u16*)p; p += (size_t)512 * HID * 2;
  u16* Wv = (u16*)p; p += (size_t)512 * HID * 2;
  u16* Wo = (u16*)p; p += (size_t)HID * HID * 2;
  u16* Qb = (u16*)p; p += (size_t)S_LEN * HID * 2;
  u16* Kb = (u16*)p; p += (size_t)S_LEN * 512 * 2;
  u16* Vt = (u16*)p; p += (size_t)S_LEN * 512 * 2;
  u16* AO = (u16*)p; p += (size_t)S_LEN * HID * 2;
  float* cs = (float*)p; p += (size_t)S_LEN * 64 * 4;
  float* sn = (float*)p; p += (size_t)S_LEN * 64 * 4;
  u16* Opart = (u16*)p; p += (size_t)2 * 16 * S_LEN * 128 * 2;  // 32 MB
  float* Mpart = (float*)p; p += (size_t)2 * 16 * S_LEN * 4;
  float* Lpart = (float*)p; p += (size_t)2 * 16 * S_LEN * 4;

  cvt_all_kernel<<<(CVT_B5 + 255) / 256, 256, 0, stream>>>(
      hx, qw, kw, vw, ow, Xb, Wq, Wk, Wv, Wo, cs, sn);

  qkv256_kernel<<<384, 512, 0, stream>>>(Xb, Wq, Wk, Wv, Qb, Kb, Vt);

  rope_qk_kernel<<<S_LEN * 20 * 16 / 256, 256, 0, stream>>>(Qb, Kb, cs, sn);

  attn_kernel<<<4096, 64, 0, stream>>>(Qb, Kb, Vt, Opart, Mpart, Lpart);
  attn_combine_kernel<<<S_LEN * 16 * 16 / 256, 256, 0, stream>>>(Opart, Mpart,
                                                                 Lpart, AO);

  o256_kernel<<<256, 512, 0, stream>>>(AO, Wo, (float*)d_out);
}